// Round 9
// baseline (690.211 us; speedup 1.0000x reference)
//
#include <hip/hip_runtime.h>
#include <hip/hip_bf16.h>

#define HH 96
#define WW 160
#define BATCH 8
#define NPIX (BATCH*HH*WW)   // 122880
#define CIN 256
#define IMG (HH*WW)          // 15360
#define PW 162               // padded width
#define PH 98                // padded height
#define PR (PH*PW)           // 15876 padded rows per image
#define PTOT (BATCH*PR)      // 127008 padded rows total

typedef short bf16x8 __attribute__((ext_vector_type(8)));
typedef float f32x4 __attribute__((ext_vector_type(4)));

__device__ __forceinline__ unsigned short f2bf(float f) {
    unsigned int u = __float_as_uint(f);
    u = (u + 0x7fffu + ((u >> 16) & 1u)) >> 16;   // RNE
    return (unsigned short)u;
}

__device__ __forceinline__ void gload16(const void* g, void* l) {
    __builtin_amdgcn_global_load_lds(
        (const __attribute__((address_space(1))) void*)g,
        (__attribute__((address_space(3))) void*)l,
        16, 0, 0);
}

// ---------------- merged prep: weights transpose + pad zero + depth-acc zero + BN fold + feature pack
// Block roles by blockIdx.x:
//   [0, 640)        : weights transpose via LDS, one output channel per block (coalesced both sides)
//                     (r8 version read w1 at stride 9 -> 9x line amplification)
//   [640, 4768)     : zero pad rows of featP/h1P (2 x 128-lane tasks per block)
//   [4768, 5248)    : zero depth accumulator out[0..NPIX)
//   5248            : BN fold scalars
//   [5249, 35969)   : NCHW f32 -> padded NHWC bf16
__global__ __launch_bounds__(256) void prep_all(
    const float* __restrict__ w1, const float* __restrict__ w2, const float* __restrict__ uw1,
    unsigned short* __restrict__ w1T, unsigned short* __restrict__ w2T, unsigned short* __restrict__ uw1T,
    unsigned int* __restrict__ featPu, unsigned int* __restrict__ h1Pu, float* __restrict__ outd,
    const float* __restrict__ b1, const float* __restrict__ g1, const float* __restrict__ be1,
    const float* __restrict__ m1, const float* __restrict__ v1,
    const float* __restrict__ b2, const float* __restrict__ g2, const float* __restrict__ be2,
    const float* __restrict__ m2, const float* __restrict__ v2,
    const float* __restrict__ ub1,
    float* __restrict__ scale1, float* __restrict__ bias1,
    float* __restrict__ scale2, float* __restrict__ bias2,
    const float* __restrict__ f, unsigned short* __restrict__ ft)
{
    __shared__ float shm[2304];          // weights: 9216 B; pack: uses first 1056 as tile[32][33]
    const int bid = blockIdx.x;
    const int t = threadIdx.x;

    if (bid < 640) {
        // one output channel co per block: src[ci*9+pos] (ci-major), dst[pos*256+ci]
        const float* src; unsigned short* dst;
        if (bid < 256)      { src = w1  + (size_t)bid * 2304;        dst = w1T  + (size_t)bid * 2304; }
        else if (bid < 512) { src = w2  + (size_t)(bid - 256) * 2304; dst = w2T  + (size_t)(bid - 256) * 2304; }
        else                { src = uw1 + (size_t)(bid - 512) * 2304; dst = uw1T + (size_t)(bid - 512) * 2304; }
        #pragma unroll
        for (int k = 0; k < 9; ++k) shm[k * 256 + t] = src[k * 256 + t];   // coalesced
        __syncthreads();
        #pragma unroll
        for (int k = 0; k < 9; ++k) {
            int d = k * 256 + t;                         // pos = d>>8, ci = d&255
            dst[d] = f2bf(shm[(d & 255) * 9 + (d >> 8)]);   // stride-9 LDS (9 coprime 32)
        }
    } else if (bid < 4768) {
        int k2 = (bid - 640) * 2 + (t >> 7);    // 0..8255, two 128-lane tasks per block
        int lane = t & 127;
        unsigned int* buf = (k2 < 4128) ? featPu : h1Pu;
        int k = (k2 < 4128) ? k2 : (k2 - 4128);
        int img = k / 516, i = k % 516;
        int py, px;
        if (i < PW)            { py = 0;      px = i; }
        else if (i < 2 * PW)   { py = PH - 1; px = i - PW; }
        else { int q = i - 2 * PW; py = 1 + (q >> 1); px = (q & 1) ? (PW - 1) : 0; }
        size_t row = (size_t)img * PR + (size_t)py * PW + px;
        buf[row * 128 + lane] = 0;              // 512 B row of zeros
    } else if (bid < 5248) {
        outd[(size_t)(bid - 4768) * 256 + t] = 0.f;   // 480*256 = NPIX
    } else if (bid == 5248) {
        if (t < 256) {
            float s1 = g1[t] * rsqrtf(v1[t] + 1e-5f);
            scale1[t] = s1;
            bias1[t]  = (b1[t] - m1[t]) * s1 + be1[t];
            float s2 = g2[t] * rsqrtf(v2[t] + 1e-5f);
            scale2[t] = s2;
            bias2[t]  = (b2[t] - m2[t]) * s2 + be2[t];
            if (t < 128) { scale1[256 + t] = 1.0f; bias1[256 + t] = ub1[t]; }
        }
    } else {
        int id = bid - 5249;                    // 30720 pack blocks
        int x0 = (id % 5) * 32;                 // W/32 = 5
        int c0 = ((id / 5) % 8) * 32;           // C/32 = 8
        int by = id / 40;                       // B*H = 768
        int b = by / HH, y = by % HH;
        int tx = t & 31, tg = t >> 5;           // tg 0..7
        const float* src = f + (((size_t)(b * CIN + c0) * HH + y) * WW) + x0;
        #pragma unroll
        for (int i = 0; i < 4; ++i) {
            int cl = tg + i * 8;
            shm[cl * 33 + tx] = src[(size_t)cl * HH * WW + tx];
        }
        __syncthreads();
        size_t rbase = (size_t)b * PR + (size_t)(y + 1) * PW + (x0 + 1);
        #pragma unroll
        for (int i = 0; i < 4; ++i) {
            int xl = tg + i * 8;
            ft[(rbase + xl) * 256 + c0 + tx] = f2bf(shm[tx * 33 + xl]);
        }
    }
}

// ---------------- 3x3 conv, implicit GEMM: 128m x 256n blocks, 64x128 per wave (r7 verified) ----
// Conv structure ladder closed (r1/r3/r5/r6/r7/r8): this exact version = 210us conv1,
// MfmaUtil 47%. r8's 3-phase counted-vmcnt pipeline REGRESSED (216.5us, VALU +3.5) — the
// 45-47% cap is the lockstep LDS-burst->MFMA-burst serialization; no source-level sync
// variant beat this 2-barrier form. Do not re-derive: occupancy >2 blocks thrashes XCD L2
// (r5/r6), 3-phase split adds VALU+barriers for nothing (r8).
// XCD swizzle: spatial s = xcd*60 + j/My -> one image per XCD.
// Row-wrap: 256-pixel tiles wrap up to twice: offset = jj + 2*((x0+jj)/WW) (+7+dx).
// B swizzle (conflict-free): lane l stages row l>>2, quarter (l&3)^((l>>3)&3); read quarter
// quad^((row>>1)&3). 17 B-slots: wave w stages 4w..4w+3, wave 3 also slot 16.
// mode 0: conv2 + FUSED depth head (partial dot with w3 via uw2, atomicAdd into uout). My=2.
// mode 1: merged conv1 (padded bf16 out, m0<256) + fused uncertainty head (m0==256), My=3.
__global__ __launch_bounds__(256, 2) void conv3x3_mfma(
    const unsigned short* __restrict__ inP,
    const unsigned short* __restrict__ wT,
    const float* __restrict__ scale, const float* __restrict__ bias,
    unsigned short* __restrict__ outT,
    float* __restrict__ uout,
    const float* __restrict__ uw2, const float* __restrict__ ub2,
    int Cout, int mode, int My)
{
    __shared__ unsigned short Alds[3 * 128 * 32];   // 24576 B, [pos][slot][...]
    __shared__ unsigned short Blds[272 * 32];       // 17408 B, 17 slots
    __shared__ float usum[2][256];

    const int t = threadIdx.x;
    const int wave = t >> 6;
    const int l = t & 63;

    const int lid = blockIdx.x;
    const int xcd = lid & 7;
    const int j = lid >> 3;
    const int n0 = (xcd * 60 + j / My) * 256;
    const int m0 = (j % My) * 128;
    const bool is_unc = (mode == 1) && (m0 == 256);

    const int b0 = n0 / IMG;
    const int rem0 = n0 % IMG;
    const int y0 = rem0 / WW;
    const int x0 = rem0 % WW;
    const int r0 = b0 * PR + (y0 + 1) * PW + (x0 + 1);   // padded row of first output pixel

    const int lrow = l >> 2;
    const int lkq = (l & 3) ^ ((l >> 3) & 3);

    // A staging per-lane source bases (two 16-row slots per wave)
    const unsigned short* asrc0 = wT + (size_t)(m0 + wave * 32 + lrow) * 9 * 256 + lkq * 8;
    const unsigned short* asrc1 = asrc0 + (size_t)16 * 9 * 256;

    char* AldsB = (char*)Alds;
    char* BldsB = (char*)Blds;
    char* aldst = AldsB + wave * 2048;   // + dx*8192 (+1024 for second slot)

    const int wm = wave >> 1, wn = wave & 1;
    const int quad = l >> 4, lane16 = l & 15;
    const int aoff = lane16 * 64 + ((quad ^ ((lane16 >> 1) & 3)) << 4);

    // B fragment base tile-rows: pixel jj -> staged index jj + 2*wraps + 7 (+dx)
    int browbase[8];
    #pragma unroll
    for (int i = 0; i < 8; ++i) {
        int jj = wn * 128 + i * 16 + lane16;
        browbase[i] = jj + 2 * ((x0 + jj) / WW) + 7;
    }

    f32x4 acc[4][8];
    #pragma unroll
    for (int mt = 0; mt < 4; ++mt)
        #pragma unroll
        for (int nt = 0; nt < 8; ++nt)
            acc[mt][nt] = (f32x4){0.f, 0.f, 0.f, 0.f};

    for (int cc = 0; cc < 8; ++cc) {
        const int ccoff = cc * 32;
        for (int dyi = 0; dyi < 3; ++dyi) {
            __syncthreads();
            // ---- stage A: 3 pos-tiles (pos = dyi*3 + dx), 6 instr/wave
            const unsigned short* a0 = asrc0 + (dyi * 3) * 256 + ccoff;
            const unsigned short* a1 = asrc1 + (dyi * 3) * 256 + ccoff;
            #pragma unroll
            for (int dxp = 0; dxp < 3; ++dxp) {
                gload16(a0 + dxp * 256, aldst + dxp * 8192);
                gload16(a1 + dxp * 256, aldst + dxp * 8192 + 1024);
            }
            // ---- stage B: 272 padded rows [r0 + (dyi-1)*PW - 8, +272), 17 slots
            const ptrdiff_t rs = (ptrdiff_t)r0 + (ptrdiff_t)(dyi - 1) * PW - 8;
            const unsigned short* bs0 = inP + (rs + lrow) * 256 + ccoff + lkq * 8;
            #pragma unroll
            for (int k = 0; k < 4; ++k) {
                const int s = wave * 4 + k;
                gload16(bs0 + s * 4096, BldsB + s * 1024);
            }
            if (wave == 3) gload16(bs0 + 16 * 4096, BldsB + 16 * 1024);   // slot 16
            __syncthreads();
            // ---- compute: 3 dx shifts x 32 MFMA
            #pragma unroll
            for (int dx = 0; dx < 3; ++dx) {
                bf16x8 af[4], bfr[8];
                #pragma unroll
                for (int mt = 0; mt < 4; ++mt)
                    af[mt] = *(const bf16x8*)(AldsB + dx * 8192 + ((wm * 4 + mt) << 10) + aoff);
                #pragma unroll
                for (int i = 0; i < 8; ++i) {
                    int row = browbase[i] + dx;
                    int ba = (row << 6) + ((quad ^ ((row >> 1) & 3)) << 4);
                    bfr[i] = *(const bf16x8*)(BldsB + ba);
                }
                #pragma unroll
                for (int mt = 0; mt < 4; ++mt)
                    #pragma unroll
                    for (int nt = 0; nt < 8; ++nt)
                        acc[mt][nt] = __builtin_amdgcn_mfma_f32_16x16x32_bf16(
                            af[mt], bfr[nt], acc[mt][nt], 0, 0, 0);
            }
        }
    }

    if (is_unc) {
        // fused uncertainty head: relu(acc+ub1) dot uw2 over all 128 channels -> softplus
        const float* ub = bias + 256;
        float s[8] = {0.f, 0.f, 0.f, 0.f, 0.f, 0.f, 0.f, 0.f};
        #pragma unroll
        for (int mt = 0; mt < 4; ++mt) {
            const int mg = wm * 64 + mt * 16 + quad * 4;
            const float4 bi = *(const float4*)&ub[mg];
            const float4 uw = *(const float4*)&uw2[mg];
            #pragma unroll
            for (int nt = 0; nt < 8; ++nt) {
                s[nt] += fmaxf(acc[mt][nt][0] + bi.x, 0.f) * uw.x
                       + fmaxf(acc[mt][nt][1] + bi.y, 0.f) * uw.y
                       + fmaxf(acc[mt][nt][2] + bi.z, 0.f) * uw.z
                       + fmaxf(acc[mt][nt][3] + bi.w, 0.f) * uw.w;
            }
        }
        #pragma unroll
        for (int nt = 0; nt < 8; ++nt) {
            s[nt] += __shfl_xor(s[nt], 16);
            s[nt] += __shfl_xor(s[nt], 32);
        }
        if (quad == 0) {
            #pragma unroll
            for (int nt = 0; nt < 8; ++nt)
                usum[wm][wn * 128 + nt * 16 + lane16] = s[nt];
        }
        __syncthreads();
        {
            float x = usum[0][t] + usum[1][t] + ub2[0];
            uout[n0 + t] = fmaxf(x, 0.f) + log1pf(expf(-fabsf(x)));
        }
        return;
    }

    if (mode == 0) {
        // fused depth head: partial dot of relu(acc*scale+bias) with w3 (in uw2) over this
        // block's 128 channels; reduce quad via shfl, wm via LDS, one atomicAdd per pixel.
        float s[8] = {0.f, 0.f, 0.f, 0.f, 0.f, 0.f, 0.f, 0.f};
        #pragma unroll
        for (int mt = 0; mt < 4; ++mt) {
            const int mg = m0 + wm * 64 + mt * 16 + quad * 4;
            const float4 sc = *(const float4*)&scale[mg];
            const float4 bi = *(const float4*)&bias[mg];
            const float4 w  = *(const float4*)&uw2[mg];
            #pragma unroll
            for (int nt = 0; nt < 8; ++nt) {
                s[nt] += fmaxf(acc[mt][nt][0] * sc.x + bi.x, 0.f) * w.x
                       + fmaxf(acc[mt][nt][1] * sc.y + bi.y, 0.f) * w.y
                       + fmaxf(acc[mt][nt][2] * sc.z + bi.z, 0.f) * w.z
                       + fmaxf(acc[mt][nt][3] * sc.w + bi.w, 0.f) * w.w;
            }
        }
        #pragma unroll
        for (int nt = 0; nt < 8; ++nt) {
            s[nt] += __shfl_xor(s[nt], 16);
            s[nt] += __shfl_xor(s[nt], 32);
        }
        if (quad == 0) {
            #pragma unroll
            for (int nt = 0; nt < 8; ++nt)
                usum[wm][wn * 128 + nt * 16 + lane16] = s[nt];
        }
        __syncthreads();
        atomicAdd(&uout[n0 + t], usum[0][t] + usum[1][t]);
        return;
    }

    // mode 1 conv output: y = relu(acc*scale + bias) -> bf16 padded rows
    size_t obase[8];
    #pragma unroll
    for (int nt = 0; nt < 8; ++nt) {
        int n = n0 + wn * 128 + nt * 16 + lane16;
        int b = n / IMG, rem = n % IMG, yy = rem / WW, xx = rem % WW;
        obase[nt] = ((size_t)(b * PH + yy + 1) * PW + (xx + 1)) * 256;
    }
    #pragma unroll
    for (int mt = 0; mt < 4; ++mt) {
        const int mg = m0 + wm * 64 + mt * 16 + quad * 4;
        const float4 sc = *(const float4*)&scale[mg];
        const float4 bi = *(const float4*)&bias[mg];
        #pragma unroll
        for (int nt = 0; nt < 8; ++nt) {
            ushort4 pk;
            pk.x = f2bf(fmaxf(acc[mt][nt][0] * sc.x + bi.x, 0.f));
            pk.y = f2bf(fmaxf(acc[mt][nt][1] * sc.y + bi.y, 0.f));
            pk.z = f2bf(fmaxf(acc[mt][nt][2] * sc.z + bi.z, 0.f));
            pk.w = f2bf(fmaxf(acc[mt][nt][3] * sc.w + bi.w, 0.f));
            *(ushort4*)&outT[obase[nt] + mg] = pk;
        }
    }
}

// ---------------- finalize depth: x -> 1/(0.01 + 9.99*sigmoid(x + b3)) in-place ----------------
__global__ __launch_bounds__(256) void depth_transform(
    float* __restrict__ out, const float* __restrict__ b3)
{
    int i = blockIdx.x * 256 + threadIdx.x;    // 480 * 256 = NPIX exactly
    float x = out[i] + b3[0];
    float sig = 1.f / (1.f + expf(-x));
    out[i] = 1.f / (0.01f + 9.99f * sig);
}

// ---------------- per-box lower-median via 4-pass radix select on float bits ----------------
// r9 rewrite: (1) division-free iteration (row per 64-lane group, stride 4 rows);
// (2) wave-aggregated histogram via ballot waterfall — depth values cluster into ~10
//     exponent bins, so the old per-element LDS atomicAdd serialized ~wh-deep on pass 0;
//     now 1 atomic per wave per distinct bin (clustered case: 1 waterfall iteration);
// (3) parallel 256-wide shfl-scan bin select replacing the serial thread-0 scan.
__global__ __launch_bounds__(256) void median_kernel(
    const float* __restrict__ depth, const int* __restrict__ bboxes, float* __restrict__ obj)
{
    const int bi = blockIdx.x;          // b*64 + box
    const int b = bi >> 6;
    const int* bb = bboxes + (size_t)bi * 4;
    int x1 = max(bb[0], 0), y1 = max(bb[1], 0);
    int x2 = min(bb[2], WW), y2 = min(bb[3], HH);
    int w = x2 - x1, h = y2 - y1;
    if (w <= 0 || h <= 0) {
        if (threadIdx.x == 0) obj[bi] = 0.f;
        return;
    }
    const int wh = w * h;
    int tgt = (wh - 1) >> 1;            // lower median index
    const float* dbase = depth + (size_t)b * HH * WW;

    __shared__ unsigned int hist[256];
    __shared__ unsigned int wsum[4];
    __shared__ unsigned int sel_prefix, sel_target;
    unsigned int prefix = 0;
    const int t = threadIdx.x;
    const int g = t >> 6, gl = t & 63;  // group (wave) and lane

    for (int pass = 0; pass < 4; ++pass) {
        const int shift = 24 - 8 * pass;
        hist[t] = 0;
        __syncthreads();
        const unsigned int mask_high = (pass == 0) ? 0u : (0xFFFFFFFFu << (shift + 8));
        const unsigned int want = prefix & mask_high;
        for (int yy = y1 + g; yy < y2; yy += 4) {
            const float* row = dbase + yy * WW;
            for (int xx = x1 + gl; xx < x2; xx += 64) {
                unsigned int uu = __float_as_uint(row[xx]);
                bool pred = (uu & mask_high) == want;
                unsigned int bin = (uu >> shift) & 255;
                unsigned long long todo = __ballot(pred);
                while (todo) {
                    int leader = __ffsll((unsigned long long)todo) - 1;
                    unsigned int lbin = __shfl(bin, leader);
                    unsigned long long same = __ballot(pred && (bin == lbin)) & todo;
                    if (gl == leader)
                        atomicAdd(&hist[lbin], (unsigned int)__popcll(same));
                    todo &= ~same;
                }
            }
        }
        __syncthreads();
        // parallel select: inclusive scan of hist across 256 threads
        unsigned int c = hist[t];
        unsigned int v = c;
        #pragma unroll
        for (int d = 1; d < 64; d <<= 1) {
            unsigned int n = __shfl_up(v, d);
            if (gl >= d) v += n;
        }
        if (gl == 63) wsum[g] = v;
        __syncthreads();
        unsigned int addv = 0;
        #pragma unroll
        for (int wv = 0; wv < 4; ++wv) addv += (wv < g) ? wsum[wv] : 0u;
        v += addv;
        unsigned int excl = v - c;
        if (excl <= (unsigned int)tgt && (unsigned int)tgt < v) {
            sel_prefix = prefix | ((unsigned int)t << shift);
            sel_target = (unsigned int)tgt - excl;
        }
        __syncthreads();
        prefix = sel_prefix;
        tgt = (int)sel_target;
        __syncthreads();
    }
    if (t == 0) obj[bi] = __uint_as_float(prefix);
}

extern "C" void kernel_launch(void* const* d_in, const int* in_sizes, int n_in,
                              void* d_out, int out_size, void* d_ws, size_t ws_size,
                              hipStream_t stream) {
    const float* features = (const float*)d_in[0];
    const int*   bboxes   = (const int*)d_in[1];
    const float* w1  = (const float*)d_in[2];
    const float* b1  = (const float*)d_in[3];
    const float* g1  = (const float*)d_in[4];
    const float* be1 = (const float*)d_in[5];
    const float* m1  = (const float*)d_in[6];
    const float* v1  = (const float*)d_in[7];
    const float* w2  = (const float*)d_in[8];
    const float* b2  = (const float*)d_in[9];
    const float* g2  = (const float*)d_in[10];
    const float* be2 = (const float*)d_in[11];
    const float* m2  = (const float*)d_in[12];
    const float* v2  = (const float*)d_in[13];
    const float* w3  = (const float*)d_in[14];
    const float* b3  = (const float*)d_in[15];
    const float* uw1 = (const float*)d_in[16];
    const float* ub1 = (const float*)d_in[17];
    const float* uw2 = (const float*)d_in[18];
    const float* ub2 = (const float*)d_in[19];
    float* out = (float*)d_out;

    char* ws = (char*)d_ws;
    // layout (bytes). Padded buffers have 8 KB read-slack gaps on both sides.
    unsigned short* featP = (unsigned short*)(ws + 8192);        // 65,028,096 -> end 65,036,288
    unsigned short* h1P   = (unsigned short*)(ws + 65044480);    // end 130,072,576
    unsigned short* w1T   = (unsigned short*)(ws + 130080768);   // 256 rows, 1,179,648 B
    unsigned short* uw1T  = w1T + 256 * 2304;                    // 128 rows right after -> combined 384
    unsigned short* w2T   = uw1T + 128 * 2304;                   // 1,179,648 B
    float* scale1 = (float*)(w2T + 589824);                      // 384
    float* bias1  = scale1 + 384;                                // 384 (256 BN-fold + 128 ub1)
    float* scale2 = bias1 + 384;                                 // 256
    float* bias2  = scale2 + 256;                                // 256

    // single merged prep launch: weights transpose + pads + depth-zero + scalars + feature pack
    prep_all<<<35969, 256, 0, stream>>>(
        w1, w2, uw1, w1T, w2T, uw1T,
        (unsigned int*)featP, (unsigned int*)h1P, out,
        b1, g1, be1, m1, v1, b2, g2, be2, m2, v2, ub1,
        scale1, bias1, scale2, bias2,
        features, featP);

    // merged conv1 (BN+ReLU, padded out) + fused uncertainty head; My=3, 1440 blocks (256n tiles)
    conv3x3_mfma<<<1440, 256, 0, stream>>>(
        featP, w1T, scale1, bias1, h1P, out + NPIX, uw2, ub2, 256, 1, 3);
    // conv2 + fused depth head: atomicAdd partial dots into out[0..NPIX); My=2, 960 blocks
    conv3x3_mfma<<<960, 256, 0, stream>>>(
        h1P, w2T, scale2, bias2, nullptr, out, w3, nullptr, 256, 0, 2);

    depth_transform<<<NPIX / 256, 256, 0, stream>>>(out, b3);
    median_kernel<<<BATCH * 64, 256, 0, stream>>>(out, bboxes, out + 2 * NPIX);
}

// Round 10
// 578.698 us; speedup vs baseline: 1.1927x; 1.1927x over previous
//
#include <hip/hip_runtime.h>
#include <hip/hip_bf16.h>

#define HH 96
#define WW 160
#define BATCH 8
#define NPIX (BATCH*HH*WW)   // 122880
#define CIN 256
#define IMG (HH*WW)          // 15360
#define PW 162               // padded width
#define PH 98                // padded height
#define PR (PH*PW)           // 15876 padded rows per image
#define PTOT (BATCH*PR)      // 127008 padded rows total

typedef short bf16x8 __attribute__((ext_vector_type(8)));
typedef float f32x4 __attribute__((ext_vector_type(4)));

__device__ __forceinline__ unsigned short f2bf(float f) {
    unsigned int u = __float_as_uint(f);
    u = (u + 0x7fffu + ((u >> 16) & 1u)) >> 16;   // RNE
    return (unsigned short)u;
}

__device__ __forceinline__ void gload16(const void* g, void* l) {
    __builtin_amdgcn_global_load_lds(
        (const __attribute__((address_space(1))) void*)g,
        (__attribute__((address_space(3))) void*)l,
        16, 0, 0);
}

// ---------------- merged prep: weights transpose + pad zero + depth-acc zero + BN fold + feature pack
// Block roles by blockIdx.x:
//   [0, 640)        : weights transpose via LDS, one output channel per block (coalesced both sides)
//   [640, 4768)     : zero pad rows of featP/h1P (2 x 128-lane tasks per block)
//   [4768, 5248)    : zero depth accumulator out[0..NPIX)
//   5248            : BN fold scalars
//   [5249, 35969)   : NCHW f32 -> padded NHWC bf16
__global__ __launch_bounds__(256) void prep_all(
    const float* __restrict__ w1, const float* __restrict__ w2, const float* __restrict__ uw1,
    unsigned short* __restrict__ w1T, unsigned short* __restrict__ w2T, unsigned short* __restrict__ uw1T,
    unsigned int* __restrict__ featPu, unsigned int* __restrict__ h1Pu, float* __restrict__ outd,
    const float* __restrict__ b1, const float* __restrict__ g1, const float* __restrict__ be1,
    const float* __restrict__ m1, const float* __restrict__ v1,
    const float* __restrict__ b2, const float* __restrict__ g2, const float* __restrict__ be2,
    const float* __restrict__ m2, const float* __restrict__ v2,
    const float* __restrict__ ub1,
    float* __restrict__ scale1, float* __restrict__ bias1,
    float* __restrict__ scale2, float* __restrict__ bias2,
    const float* __restrict__ f, unsigned short* __restrict__ ft)
{
    __shared__ float shm[2304];          // weights: 9216 B; pack: uses first 1056 as tile[32][33]
    const int bid = blockIdx.x;
    const int t = threadIdx.x;

    if (bid < 640) {
        // one output channel co per block: src[ci*9+pos] (ci-major), dst[pos*256+ci]
        const float* src; unsigned short* dst;
        if (bid < 256)      { src = w1  + (size_t)bid * 2304;        dst = w1T  + (size_t)bid * 2304; }
        else if (bid < 512) { src = w2  + (size_t)(bid - 256) * 2304; dst = w2T  + (size_t)(bid - 256) * 2304; }
        else                { src = uw1 + (size_t)(bid - 512) * 2304; dst = uw1T + (size_t)(bid - 512) * 2304; }
        #pragma unroll
        for (int k = 0; k < 9; ++k) shm[k * 256 + t] = src[k * 256 + t];   // coalesced
        __syncthreads();
        #pragma unroll
        for (int k = 0; k < 9; ++k) {
            int d = k * 256 + t;                         // pos = d>>8, ci = d&255
            dst[d] = f2bf(shm[(d & 255) * 9 + (d >> 8)]);   // stride-9 LDS (9 coprime 32)
        }
    } else if (bid < 4768) {
        int k2 = (bid - 640) * 2 + (t >> 7);    // 0..8255, two 128-lane tasks per block
        int lane = t & 127;
        unsigned int* buf = (k2 < 4128) ? featPu : h1Pu;
        int k = (k2 < 4128) ? k2 : (k2 - 4128);
        int img = k / 516, i = k % 516;
        int py, px;
        if (i < PW)            { py = 0;      px = i; }
        else if (i < 2 * PW)   { py = PH - 1; px = i - PW; }
        else { int q = i - 2 * PW; py = 1 + (q >> 1); px = (q & 1) ? (PW - 1) : 0; }
        size_t row = (size_t)img * PR + (size_t)py * PW + px;
        buf[row * 128 + lane] = 0;              // 512 B row of zeros
    } else if (bid < 5248) {
        outd[(size_t)(bid - 4768) * 256 + t] = 0.f;   // 480*256 = NPIX
    } else if (bid == 5248) {
        if (t < 256) {
            float s1 = g1[t] * rsqrtf(v1[t] + 1e-5f);
            scale1[t] = s1;
            bias1[t]  = (b1[t] - m1[t]) * s1 + be1[t];
            float s2 = g2[t] * rsqrtf(v2[t] + 1e-5f);
            scale2[t] = s2;
            bias2[t]  = (b2[t] - m2[t]) * s2 + be2[t];
            if (t < 128) { scale1[256 + t] = 1.0f; bias1[256 + t] = ub1[t]; }
        }
    } else {
        int id = bid - 5249;                    // 30720 pack blocks
        int x0 = (id % 5) * 32;                 // W/32 = 5
        int c0 = ((id / 5) % 8) * 32;           // C/32 = 8
        int by = id / 40;                       // B*H = 768
        int b = by / HH, y = by % HH;
        int tx = t & 31, tg = t >> 5;           // tg 0..7
        const float* src = f + (((size_t)(b * CIN + c0) * HH + y) * WW) + x0;
        #pragma unroll
        for (int i = 0; i < 4; ++i) {
            int cl = tg + i * 8;
            shm[cl * 33 + tx] = src[(size_t)cl * HH * WW + tx];
        }
        __syncthreads();
        size_t rbase = (size_t)b * PR + (size_t)(y + 1) * PW + (x0 + 1);
        #pragma unroll
        for (int i = 0; i < 4; ++i) {
            int xl = tg + i * 8;
            ft[(rbase + xl) * 256 + c0 + tx] = f2bf(shm[tx * 33 + xl]);
        }
    }
}

// ---------------- 3x3 conv, implicit GEMM: 128m x 256n blocks, 64x128 per wave (r7 verified) ----
// Conv structure ladder closed (r1/r3/r5/r6/r7/r8): this exact version = 210us conv1,
// MfmaUtil 47%. Do not re-derive: occupancy >2 blocks thrashes XCD L2 (r5/r6), 3-phase
// counted-vmcnt split adds VALU+barriers for nothing (r8).
// XCD swizzle: spatial s = xcd*60 + j/My -> one image per XCD.
// Row-wrap: 256-pixel tiles wrap up to twice: offset = jj + 2*((x0+jj)/WW) (+7+dx).
// B swizzle (conflict-free): lane l stages row l>>2, quarter (l&3)^((l>>3)&3); read quarter
// quad^((row>>1)&3). 17 B-slots: wave w stages 4w..4w+3, wave 3 also slot 16.
// mode 0: conv2 + FUSED depth head (partial dot with w3 via uw2, atomicAdd into uout). My=2.
// mode 1: merged conv1 (padded bf16 out, m0<256) + fused uncertainty head (m0==256), My=3.
__global__ __launch_bounds__(256, 2) void conv3x3_mfma(
    const unsigned short* __restrict__ inP,
    const unsigned short* __restrict__ wT,
    const float* __restrict__ scale, const float* __restrict__ bias,
    unsigned short* __restrict__ outT,
    float* __restrict__ uout,
    const float* __restrict__ uw2, const float* __restrict__ ub2,
    int Cout, int mode, int My)
{
    __shared__ unsigned short Alds[3 * 128 * 32];   // 24576 B, [pos][slot][...]
    __shared__ unsigned short Blds[272 * 32];       // 17408 B, 17 slots
    __shared__ float usum[2][256];

    const int t = threadIdx.x;
    const int wave = t >> 6;
    const int l = t & 63;

    const int lid = blockIdx.x;
    const int xcd = lid & 7;
    const int j = lid >> 3;
    const int n0 = (xcd * 60 + j / My) * 256;
    const int m0 = (j % My) * 128;
    const bool is_unc = (mode == 1) && (m0 == 256);

    const int b0 = n0 / IMG;
    const int rem0 = n0 % IMG;
    const int y0 = rem0 / WW;
    const int x0 = rem0 % WW;
    const int r0 = b0 * PR + (y0 + 1) * PW + (x0 + 1);   // padded row of first output pixel

    const int lrow = l >> 2;
    const int lkq = (l & 3) ^ ((l >> 3) & 3);

    // A staging per-lane source bases (two 16-row slots per wave)
    const unsigned short* asrc0 = wT + (size_t)(m0 + wave * 32 + lrow) * 9 * 256 + lkq * 8;
    const unsigned short* asrc1 = asrc0 + (size_t)16 * 9 * 256;

    char* AldsB = (char*)Alds;
    char* BldsB = (char*)Blds;
    char* aldst = AldsB + wave * 2048;   // + dx*8192 (+1024 for second slot)

    const int wm = wave >> 1, wn = wave & 1;
    const int quad = l >> 4, lane16 = l & 15;
    const int aoff = lane16 * 64 + ((quad ^ ((lane16 >> 1) & 3)) << 4);

    // B fragment base tile-rows: pixel jj -> staged index jj + 2*wraps + 7 (+dx)
    int browbase[8];
    #pragma unroll
    for (int i = 0; i < 8; ++i) {
        int jj = wn * 128 + i * 16 + lane16;
        browbase[i] = jj + 2 * ((x0 + jj) / WW) + 7;
    }

    f32x4 acc[4][8];
    #pragma unroll
    for (int mt = 0; mt < 4; ++mt)
        #pragma unroll
        for (int nt = 0; nt < 8; ++nt)
            acc[mt][nt] = (f32x4){0.f, 0.f, 0.f, 0.f};

    for (int cc = 0; cc < 8; ++cc) {
        const int ccoff = cc * 32;
        for (int dyi = 0; dyi < 3; ++dyi) {
            __syncthreads();
            // ---- stage A: 3 pos-tiles (pos = dyi*3 + dx), 6 instr/wave
            const unsigned short* a0 = asrc0 + (dyi * 3) * 256 + ccoff;
            const unsigned short* a1 = asrc1 + (dyi * 3) * 256 + ccoff;
            #pragma unroll
            for (int dxp = 0; dxp < 3; ++dxp) {
                gload16(a0 + dxp * 256, aldst + dxp * 8192);
                gload16(a1 + dxp * 256, aldst + dxp * 8192 + 1024);
            }
            // ---- stage B: 272 padded rows [r0 + (dyi-1)*PW - 8, +272), 17 slots
            const ptrdiff_t rs = (ptrdiff_t)r0 + (ptrdiff_t)(dyi - 1) * PW - 8;
            const unsigned short* bs0 = inP + (rs + lrow) * 256 + ccoff + lkq * 8;
            #pragma unroll
            for (int k = 0; k < 4; ++k) {
                const int s = wave * 4 + k;
                gload16(bs0 + s * 4096, BldsB + s * 1024);
            }
            if (wave == 3) gload16(bs0 + 16 * 4096, BldsB + 16 * 1024);   // slot 16
            __syncthreads();
            // ---- compute: 3 dx shifts x 32 MFMA
            #pragma unroll
            for (int dx = 0; dx < 3; ++dx) {
                bf16x8 af[4], bfr[8];
                #pragma unroll
                for (int mt = 0; mt < 4; ++mt)
                    af[mt] = *(const bf16x8*)(AldsB + dx * 8192 + ((wm * 4 + mt) << 10) + aoff);
                #pragma unroll
                for (int i = 0; i < 8; ++i) {
                    int row = browbase[i] + dx;
                    int ba = (row << 6) + ((quad ^ ((row >> 1) & 3)) << 4);
                    bfr[i] = *(const bf16x8*)(BldsB + ba);
                }
                #pragma unroll
                for (int mt = 0; mt < 4; ++mt)
                    #pragma unroll
                    for (int nt = 0; nt < 8; ++nt)
                        acc[mt][nt] = __builtin_amdgcn_mfma_f32_16x16x32_bf16(
                            af[mt], bfr[nt], acc[mt][nt], 0, 0, 0);
            }
        }
    }

    if (is_unc) {
        // fused uncertainty head: relu(acc+ub1) dot uw2 over all 128 channels -> softplus
        const float* ub = bias + 256;
        float s[8] = {0.f, 0.f, 0.f, 0.f, 0.f, 0.f, 0.f, 0.f};
        #pragma unroll
        for (int mt = 0; mt < 4; ++mt) {
            const int mg = wm * 64 + mt * 16 + quad * 4;
            const float4 bi = *(const float4*)&ub[mg];
            const float4 uw = *(const float4*)&uw2[mg];
            #pragma unroll
            for (int nt = 0; nt < 8; ++nt) {
                s[nt] += fmaxf(acc[mt][nt][0] + bi.x, 0.f) * uw.x
                       + fmaxf(acc[mt][nt][1] + bi.y, 0.f) * uw.y
                       + fmaxf(acc[mt][nt][2] + bi.z, 0.f) * uw.z
                       + fmaxf(acc[mt][nt][3] + bi.w, 0.f) * uw.w;
            }
        }
        #pragma unroll
        for (int nt = 0; nt < 8; ++nt) {
            s[nt] += __shfl_xor(s[nt], 16);
            s[nt] += __shfl_xor(s[nt], 32);
        }
        if (quad == 0) {
            #pragma unroll
            for (int nt = 0; nt < 8; ++nt)
                usum[wm][wn * 128 + nt * 16 + lane16] = s[nt];
        }
        __syncthreads();
        {
            float x = usum[0][t] + usum[1][t] + ub2[0];
            uout[n0 + t] = fmaxf(x, 0.f) + log1pf(expf(-fabsf(x)));
        }
        return;
    }

    if (mode == 0) {
        // fused depth head: partial dot of relu(acc*scale+bias) with w3 (in uw2) over this
        // block's 128 channels; reduce quad via shfl, wm via LDS, one atomicAdd per pixel.
        float s[8] = {0.f, 0.f, 0.f, 0.f, 0.f, 0.f, 0.f, 0.f};
        #pragma unroll
        for (int mt = 0; mt < 4; ++mt) {
            const int mg = m0 + wm * 64 + mt * 16 + quad * 4;
            const float4 sc = *(const float4*)&scale[mg];
            const float4 bi = *(const float4*)&bias[mg];
            const float4 w  = *(const float4*)&uw2[mg];
            #pragma unroll
            for (int nt = 0; nt < 8; ++nt) {
                s[nt] += fmaxf(acc[mt][nt][0] * sc.x + bi.x, 0.f) * w.x
                       + fmaxf(acc[mt][nt][1] * sc.y + bi.y, 0.f) * w.y
                       + fmaxf(acc[mt][nt][2] * sc.z + bi.z, 0.f) * w.z
                       + fmaxf(acc[mt][nt][3] * sc.w + bi.w, 0.f) * w.w;
            }
        }
        #pragma unroll
        for (int nt = 0; nt < 8; ++nt) {
            s[nt] += __shfl_xor(s[nt], 16);
            s[nt] += __shfl_xor(s[nt], 32);
        }
        if (quad == 0) {
            #pragma unroll
            for (int nt = 0; nt < 8; ++nt)
                usum[wm][wn * 128 + nt * 16 + lane16] = s[nt];
        }
        __syncthreads();
        atomicAdd(&uout[n0 + t], usum[0][t] + usum[1][t]);
        return;
    }

    // mode 1 conv output: y = relu(acc*scale + bias) -> bf16 padded rows
    size_t obase[8];
    #pragma unroll
    for (int nt = 0; nt < 8; ++nt) {
        int n = n0 + wn * 128 + nt * 16 + lane16;
        int b = n / IMG, rem = n % IMG, yy = rem / WW, xx = rem % WW;
        obase[nt] = ((size_t)(b * PH + yy + 1) * PW + (xx + 1)) * 256;
    }
    #pragma unroll
    for (int mt = 0; mt < 4; ++mt) {
        const int mg = m0 + wm * 64 + mt * 16 + quad * 4;
        const float4 sc = *(const float4*)&scale[mg];
        const float4 bi = *(const float4*)&bias[mg];
        #pragma unroll
        for (int nt = 0; nt < 8; ++nt) {
            ushort4 pk;
            pk.x = f2bf(fmaxf(acc[mt][nt][0] * sc.x + bi.x, 0.f));
            pk.y = f2bf(fmaxf(acc[mt][nt][1] * sc.y + bi.y, 0.f));
            pk.z = f2bf(fmaxf(acc[mt][nt][2] * sc.z + bi.z, 0.f));
            pk.w = f2bf(fmaxf(acc[mt][nt][3] * sc.w + bi.w, 0.f));
            *(ushort4*)&outT[obase[nt] + mg] = pk;
        }
    }
}

// ---------------- finalize depth: x -> 1/(0.01 + 9.99*sigmoid(x + b3)) in-place ----------------
__global__ __launch_bounds__(256) void depth_transform(
    float* __restrict__ out, const float* __restrict__ b3)
{
    int i = blockIdx.x * 256 + threadIdx.x;    // 480 * 256 = NPIX exactly
    float x = out[i] + b3[0];
    float sig = 1.f / (1.f + expf(-x));
    out[i] = 1.f / (0.01f + 9.99f * sig);
}

// ---------------- per-box lower-median via 4-pass radix select on float bits ----------------
// r10 median: two-tier histogram accumulation, cheap in BOTH data regimes (r9 lesson — the
// ballot waterfall was O(#distinct-bins) serial and degenerated on uniform mantissa bins):
//   fast path: strip's active lanes all share one bin (pass-0/clustered case) -> ONE leader
//              atomic with popcount;
//   else: per-lane atomicAdd into this WAVE's private 256-bin histogram (no cross-wave
//         contention; uniform bins spread across banks -> few conflicts).
// Bin select via parallel 256-wide shfl scan (no serial thread-0 loop).
__global__ __launch_bounds__(256) void median_kernel(
    const float* __restrict__ depth, const int* __restrict__ bboxes, float* __restrict__ obj)
{
    const int bi = blockIdx.x;          // b*64 + box
    const int b = bi >> 6;
    const int* bb = bboxes + (size_t)bi * 4;
    int x1 = max(bb[0], 0), y1 = max(bb[1], 0);
    int x2 = min(bb[2], WW), y2 = min(bb[3], HH);
    int w = x2 - x1, h = y2 - y1;
    if (w <= 0 || h <= 0) {
        if (threadIdx.x == 0) obj[bi] = 0.f;
        return;
    }
    const int wh = w * h;
    int tgt = (wh - 1) >> 1;            // lower median index
    const float* dbase = depth + (size_t)b * HH * WW;

    __shared__ unsigned int hist[4][256];   // wave-private histograms
    __shared__ unsigned int wsum[4];
    __shared__ unsigned int sel_prefix, sel_target;
    unsigned int prefix = 0;
    const int t = threadIdx.x;
    const int g = t >> 6, gl = t & 63;  // wave and lane

    for (int pass = 0; pass < 4; ++pass) {
        const int shift = 24 - 8 * pass;
        #pragma unroll
        for (int k = 0; k < 4; ++k) hist[k][t & 255] = 0;   // t<256: each thread zeros 4 entries
        __syncthreads();
        const unsigned int mask_high = (pass == 0) ? 0u : (0xFFFFFFFFu << (shift + 8));
        const unsigned int want = prefix & mask_high;
        for (int yy = y1 + g; yy < y2; yy += 4) {
            const float* row = dbase + yy * WW;
            for (int xx = x1 + gl; xx < x2; xx += 64) {
                unsigned int uu = __float_as_uint(row[xx]);
                bool pred = (uu & mask_high) == want;
                unsigned int bin = (uu >> shift) & 255;
                unsigned long long act = __ballot(pred);
                if (act != 0ull) {
                    int leader = __ffsll(act) - 1;
                    unsigned int lbin = __shfl(bin, leader);
                    unsigned long long same = __ballot(pred && (bin == lbin));
                    if (same == act) {
                        // all active lanes share one bin: single atomic by leader
                        if (gl == leader)
                            atomicAdd(&hist[g][lbin], (unsigned int)__popcll(act));
                    } else if (pred) {
                        atomicAdd(&hist[g][bin], 1u);
                    }
                }
            }
        }
        __syncthreads();
        // parallel select: sum 4 wave-hists, inclusive scan across 256 threads
        unsigned int c = hist[0][t] + hist[1][t] + hist[2][t] + hist[3][t];
        unsigned int v = c;
        #pragma unroll
        for (int d = 1; d < 64; d <<= 1) {
            unsigned int n = __shfl_up(v, d);
            if (gl >= d) v += n;
        }
        if (gl == 63) wsum[g] = v;
        __syncthreads();
        unsigned int addv = 0;
        #pragma unroll
        for (int wv = 0; wv < 4; ++wv) addv += (wv < g) ? wsum[wv] : 0u;
        v += addv;
        unsigned int excl = v - c;
        if (excl <= (unsigned int)tgt && (unsigned int)tgt < v) {
            sel_prefix = prefix | ((unsigned int)t << shift);
            sel_target = (unsigned int)tgt - excl;
        }
        __syncthreads();
        prefix = sel_prefix;
        tgt = (int)sel_target;
        __syncthreads();
    }
    if (t == 0) obj[bi] = __uint_as_float(prefix);
}

extern "C" void kernel_launch(void* const* d_in, const int* in_sizes, int n_in,
                              void* d_out, int out_size, void* d_ws, size_t ws_size,
                              hipStream_t stream) {
    const float* features = (const float*)d_in[0];
    const int*   bboxes   = (const int*)d_in[1];
    const float* w1  = (const float*)d_in[2];
    const float* b1  = (const float*)d_in[3];
    const float* g1  = (const float*)d_in[4];
    const float* be1 = (const float*)d_in[5];
    const float* m1  = (const float*)d_in[6];
    const float* v1  = (const float*)d_in[7];
    const float* w2  = (const float*)d_in[8];
    const float* b2  = (const float*)d_in[9];
    const float* g2  = (const float*)d_in[10];
    const float* be2 = (const float*)d_in[11];
    const float* m2  = (const float*)d_in[12];
    const float* v2  = (const float*)d_in[13];
    const float* w3  = (const float*)d_in[14];
    const float* b3  = (const float*)d_in[15];
    const float* uw1 = (const float*)d_in[16];
    const float* ub1 = (const float*)d_in[17];
    const float* uw2 = (const float*)d_in[18];
    const float* ub2 = (const float*)d_in[19];
    float* out = (float*)d_out;

    char* ws = (char*)d_ws;
    // layout (bytes). Padded buffers have 8 KB read-slack gaps on both sides.
    unsigned short* featP = (unsigned short*)(ws + 8192);        // 65,028,096 -> end 65,036,288
    unsigned short* h1P   = (unsigned short*)(ws + 65044480);    // end 130,072,576
    unsigned short* w1T   = (unsigned short*)(ws + 130080768);   // 256 rows, 1,179,648 B
    unsigned short* uw1T  = w1T + 256 * 2304;                    // 128 rows right after -> combined 384
    unsigned short* w2T   = uw1T + 128 * 2304;                   // 1,179,648 B
    float* scale1 = (float*)(w2T + 589824);                      // 384
    float* bias1  = scale1 + 384;                                // 384 (256 BN-fold + 128 ub1)
    float* scale2 = bias1 + 384;                                 // 256
    float* bias2  = scale2 + 256;                                // 256

    // single merged prep launch: weights transpose + pads + depth-zero + scalars + feature pack
    prep_all<<<35969, 256, 0, stream>>>(
        w1, w2, uw1, w1T, w2T, uw1T,
        (unsigned int*)featP, (unsigned int*)h1P, out,
        b1, g1, be1, m1, v1, b2, g2, be2, m2, v2, ub1,
        scale1, bias1, scale2, bias2,
        features, featP);

    // merged conv1 (BN+ReLU, padded out) + fused uncertainty head; My=3, 1440 blocks (256n tiles)
    conv3x3_mfma<<<1440, 256, 0, stream>>>(
        featP, w1T, scale1, bias1, h1P, out + NPIX, uw2, ub2, 256, 1, 3);
    // conv2 + fused depth head: atomicAdd partial dots into out[0..NPIX); My=2, 960 blocks
    conv3x3_mfma<<<960, 256, 0, stream>>>(
        h1P, w2T, scale2, bias2, nullptr, out, w3, nullptr, 256, 0, 2);

    depth_transform<<<NPIX / 256, 256, 0, stream>>>(out, b3);
    median_kernel<<<BATCH * 64, 256, 0, stream>>>(out, bboxes, out + 2 * NPIX);
}

// Round 11
// 566.452 us; speedup vs baseline: 1.2185x; 1.0216x over previous
//
#include <hip/hip_runtime.h>
#include <hip/hip_bf16.h>

#define HH 96
#define WW 160
#define BATCH 8
#define NPIX (BATCH*HH*WW)   // 122880
#define CIN 256
#define IMG (HH*WW)          // 15360
#define PW 162               // padded width
#define PH 98                // padded height
#define PR (PH*PW)           // 15876 padded rows per image
#define PTOT (BATCH*PR)      // 127008 padded rows total

typedef short bf16x8 __attribute__((ext_vector_type(8)));
typedef float f32x4 __attribute__((ext_vector_type(4)));

__device__ __forceinline__ unsigned short f2bf(float f) {
    unsigned int u = __float_as_uint(f);
    u = (u + 0x7fffu + ((u >> 16) & 1u)) >> 16;   // RNE
    return (unsigned short)u;
}

__device__ __forceinline__ void gload16(const void* g, void* l) {
    __builtin_amdgcn_global_load_lds(
        (const __attribute__((address_space(1))) void*)g,
        (__attribute__((address_space(3))) void*)l,
        16, 0, 0);
}

// ---------------- merged prep: weights transpose + pad zero + racc zero + BN fold + feature pack
// Block roles by blockIdx.x:
//   [0, 640)        : weights transpose via LDS, one output channel per block (coalesced both sides)
//   [640, 4768)     : zero pad rows of featP/h1P (2 x 128-lane tasks per block)
//   [4768, 5248)    : zero raw depth accumulator racc[0..NPIX)
//   5248            : BN fold scalars
//   [5249, 9089)    : NCHW f32 -> padded NHWC bf16, v2 (r11): one block per (b,y,x-chunk32)
//                     covering ALL 256 channels. float4 loads; XOR-swizzled LDS tile
//                     (g(c) = (((c>>3)&7)^((c>>6)&3))<<2, conflict-free for stride-33 f32 rows
//                     read at 4-row/lane stride); stores are FULL 512B/wave ushort4 pixel rows
//                     (old pack: 64B/wave store fragments, 8x more blocks).
__global__ __launch_bounds__(256) void prep_all(
    const float* __restrict__ w1, const float* __restrict__ w2, const float* __restrict__ uw1,
    unsigned short* __restrict__ w1T, unsigned short* __restrict__ w2T, unsigned short* __restrict__ uw1T,
    unsigned int* __restrict__ featPu, unsigned int* __restrict__ h1Pu, float* __restrict__ racc,
    const float* __restrict__ b1, const float* __restrict__ g1, const float* __restrict__ be1,
    const float* __restrict__ m1, const float* __restrict__ v1,
    const float* __restrict__ b2, const float* __restrict__ g2, const float* __restrict__ be2,
    const float* __restrict__ m2, const float* __restrict__ v2,
    const float* __restrict__ ub1,
    float* __restrict__ scale1, float* __restrict__ bias1,
    float* __restrict__ scale2, float* __restrict__ bias2,
    const float* __restrict__ f, unsigned short* __restrict__ ft)
{
    __shared__ float shm[8448];          // pack v2: 256x33 f32 tile (33792 B); other roles use prefix
    const int bid = blockIdx.x;
    const int t = threadIdx.x;

    if (bid < 640) {
        // one output channel co per block: src[ci*9+pos] (ci-major), dst[pos*256+ci]
        const float* src; unsigned short* dst;
        if (bid < 256)      { src = w1  + (size_t)bid * 2304;        dst = w1T  + (size_t)bid * 2304; }
        else if (bid < 512) { src = w2  + (size_t)(bid - 256) * 2304; dst = w2T  + (size_t)(bid - 256) * 2304; }
        else                { src = uw1 + (size_t)(bid - 512) * 2304; dst = uw1T + (size_t)(bid - 512) * 2304; }
        #pragma unroll
        for (int k = 0; k < 9; ++k) shm[k * 256 + t] = src[k * 256 + t];   // coalesced
        __syncthreads();
        #pragma unroll
        for (int k = 0; k < 9; ++k) {
            int d = k * 256 + t;                         // pos = d>>8, ci = d&255
            dst[d] = f2bf(shm[(d & 255) * 9 + (d >> 8)]);   // stride-9 LDS (9 coprime 32)
        }
    } else if (bid < 4768) {
        int k2 = (bid - 640) * 2 + (t >> 7);    // 0..8255, two 128-lane tasks per block
        int lane = t & 127;
        unsigned int* buf = (k2 < 4128) ? featPu : h1Pu;
        int k = (k2 < 4128) ? k2 : (k2 - 4128);
        int img = k / 516, i = k % 516;
        int py, px;
        if (i < PW)            { py = 0;      px = i; }
        else if (i < 2 * PW)   { py = PH - 1; px = i - PW; }
        else { int q = i - 2 * PW; py = 1 + (q >> 1); px = (q & 1) ? (PW - 1) : 0; }
        size_t row = (size_t)img * PR + (size_t)py * PW + px;
        buf[row * 128 + lane] = 0;              // 512 B row of zeros
    } else if (bid < 5248) {
        racc[(size_t)(bid - 4768) * 256 + t] = 0.f;   // 480*256 = NPIX
    } else if (bid == 5248) {
        if (t < 256) {
            float s1 = g1[t] * rsqrtf(v1[t] + 1e-5f);
            scale1[t] = s1;
            bias1[t]  = (b1[t] - m1[t]) * s1 + be1[t];
            float s2 = g2[t] * rsqrtf(v2[t] + 1e-5f);
            scale2[t] = s2;
            bias2[t]  = (b2[t] - m2[t]) * s2 + be2[t];
            if (t < 128) { scale1[256 + t] = 1.0f; bias1[256 + t] = ub1[t]; }
        }
    } else {
        int id = bid - 5249;                    // 3840 pack blocks
        int x0 = (id % 5) * 32;                 // W/32 = 5
        int by = id / 5;                        // B*H = 768
        int b = by / HH, y = by % HH;
        // ---- load: 256 rows x 32 px, float4 per thread x 8, XOR-swizzled LDS writes
        const int rl = t >> 3, ch = t & 7;      // row-in-group, 16B chunk
        #pragma unroll
        for (int k = 0; k < 8; ++k) {
            int r = k * 32 + rl;
            const float4 v = *(const float4*)(f + ((size_t)(b * CIN + r) * HH + y) * WW + x0 + ch * 4);
            int g = (((r >> 3) & 7) ^ ((r >> 6) & 3)) << 2;
            int base = r * 33;
            int p0 = ch * 4;
            shm[base + ((p0 + 0) ^ g)] = v.x;
            shm[base + ((p0 + 1) ^ g)] = v.y;
            shm[base + ((p0 + 2) ^ g)] = v.z;
            shm[base + ((p0 + 3) ^ g)] = v.w;
        }
        __syncthreads();
        // ---- store: one full 512B pixel row (256 ch) per wave per iteration
        const int wv = t >> 6, l = t & 63;
        const int c0 = l * 4;
        const int g = (((c0 >> 3) & 7) ^ ((c0 >> 6) & 3)) << 2;   // const over c0..c0+3
        size_t rbase = (size_t)b * PR + (size_t)(y + 1) * PW + (x0 + 1);
        #pragma unroll
        for (int q = 0; q < 8; ++q) {
            int p = q * 4 + wv;
            ushort4 pk;
            pk.x = f2bf(shm[(c0 + 0) * 33 + (p ^ g)]);
            pk.y = f2bf(shm[(c0 + 1) * 33 + (p ^ g)]);
            pk.z = f2bf(shm[(c0 + 2) * 33 + (p ^ g)]);
            pk.w = f2bf(shm[(c0 + 3) * 33 + (p ^ g)]);
            *(ushort4*)&ft[(rbase + p) * 256 + c0] = pk;
        }
    }
}

// ---------------- 3x3 conv, implicit GEMM: 128m x 256n blocks, 64x128 per wave (r7 verified) ----
// Conv structure ladder closed (r1/r3/r5/r6/r7/r8): this exact version = 210us conv1,
// MfmaUtil 47%. Do not re-derive: occupancy >2 blocks thrashes XCD L2 (r5/r6), 3-phase
// counted-vmcnt split adds VALU+barriers for nothing (r8).
// XCD swizzle: spatial s = xcd*60 + j/My -> one image per XCD.
// Row-wrap: 256-pixel tiles wrap up to twice: offset = jj + 2*((x0+jj)/WW) (+7+dx).
// B swizzle (conflict-free): lane l stages row l>>2, quarter (l&3)^((l>>3)&3); read quarter
// quad^((row>>1)&3). 17 B-slots: wave w stages 4w..4w+3, wave 3 also slot 16.
// mode 0: conv2 + FUSED depth head (partial dot with w3 via uw2, atomicAdd RAW sums into
//         uout=racc; transform deferred to finalize). My=2.
// mode 1: merged conv1 (padded bf16 out, m0<256) + fused uncertainty head (m0==256), My=3.
__global__ __launch_bounds__(256, 2) void conv3x3_mfma(
    const unsigned short* __restrict__ inP,
    const unsigned short* __restrict__ wT,
    const float* __restrict__ scale, const float* __restrict__ bias,
    unsigned short* __restrict__ outT,
    float* __restrict__ uout,
    const float* __restrict__ uw2, const float* __restrict__ ub2,
    int Cout, int mode, int My)
{
    __shared__ unsigned short Alds[3 * 128 * 32];   // 24576 B, [pos][slot][...]
    __shared__ unsigned short Blds[272 * 32];       // 17408 B, 17 slots
    __shared__ float usum[2][256];

    const int t = threadIdx.x;
    const int wave = t >> 6;
    const int l = t & 63;

    const int lid = blockIdx.x;
    const int xcd = lid & 7;
    const int j = lid >> 3;
    const int n0 = (xcd * 60 + j / My) * 256;
    const int m0 = (j % My) * 128;
    const bool is_unc = (mode == 1) && (m0 == 256);

    const int b0 = n0 / IMG;
    const int rem0 = n0 % IMG;
    const int y0 = rem0 / WW;
    const int x0 = rem0 % WW;
    const int r0 = b0 * PR + (y0 + 1) * PW + (x0 + 1);   // padded row of first output pixel

    const int lrow = l >> 2;
    const int lkq = (l & 3) ^ ((l >> 3) & 3);

    // A staging per-lane source bases (two 16-row slots per wave)
    const unsigned short* asrc0 = wT + (size_t)(m0 + wave * 32 + lrow) * 9 * 256 + lkq * 8;
    const unsigned short* asrc1 = asrc0 + (size_t)16 * 9 * 256;

    char* AldsB = (char*)Alds;
    char* BldsB = (char*)Blds;
    char* aldst = AldsB + wave * 2048;   // + dx*8192 (+1024 for second slot)

    const int wm = wave >> 1, wn = wave & 1;
    const int quad = l >> 4, lane16 = l & 15;
    const int aoff = lane16 * 64 + ((quad ^ ((lane16 >> 1) & 3)) << 4);

    // B fragment base tile-rows: pixel jj -> staged index jj + 2*wraps + 7 (+dx)
    int browbase[8];
    #pragma unroll
    for (int i = 0; i < 8; ++i) {
        int jj = wn * 128 + i * 16 + lane16;
        browbase[i] = jj + 2 * ((x0 + jj) / WW) + 7;
    }

    f32x4 acc[4][8];
    #pragma unroll
    for (int mt = 0; mt < 4; ++mt)
        #pragma unroll
        for (int nt = 0; nt < 8; ++nt)
            acc[mt][nt] = (f32x4){0.f, 0.f, 0.f, 0.f};

    for (int cc = 0; cc < 8; ++cc) {
        const int ccoff = cc * 32;
        for (int dyi = 0; dyi < 3; ++dyi) {
            __syncthreads();
            // ---- stage A: 3 pos-tiles (pos = dyi*3 + dx), 6 instr/wave
            const unsigned short* a0 = asrc0 + (dyi * 3) * 256 + ccoff;
            const unsigned short* a1 = asrc1 + (dyi * 3) * 256 + ccoff;
            #pragma unroll
            for (int dxp = 0; dxp < 3; ++dxp) {
                gload16(a0 + dxp * 256, aldst + dxp * 8192);
                gload16(a1 + dxp * 256, aldst + dxp * 8192 + 1024);
            }
            // ---- stage B: 272 padded rows [r0 + (dyi-1)*PW - 8, +272), 17 slots
            const ptrdiff_t rs = (ptrdiff_t)r0 + (ptrdiff_t)(dyi - 1) * PW - 8;
            const unsigned short* bs0 = inP + (rs + lrow) * 256 + ccoff + lkq * 8;
            #pragma unroll
            for (int k = 0; k < 4; ++k) {
                const int s = wave * 4 + k;
                gload16(bs0 + s * 4096, BldsB + s * 1024);
            }
            if (wave == 3) gload16(bs0 + 16 * 4096, BldsB + 16 * 1024);   // slot 16
            __syncthreads();
            // ---- compute: 3 dx shifts x 32 MFMA
            #pragma unroll
            for (int dx = 0; dx < 3; ++dx) {
                bf16x8 af[4], bfr[8];
                #pragma unroll
                for (int mt = 0; mt < 4; ++mt)
                    af[mt] = *(const bf16x8*)(AldsB + dx * 8192 + ((wm * 4 + mt) << 10) + aoff);
                #pragma unroll
                for (int i = 0; i < 8; ++i) {
                    int row = browbase[i] + dx;
                    int ba = (row << 6) + ((quad ^ ((row >> 1) & 3)) << 4);
                    bfr[i] = *(const bf16x8*)(BldsB + ba);
                }
                #pragma unroll
                for (int mt = 0; mt < 4; ++mt)
                    #pragma unroll
                    for (int nt = 0; nt < 8; ++nt)
                        acc[mt][nt] = __builtin_amdgcn_mfma_f32_16x16x32_bf16(
                            af[mt], bfr[nt], acc[mt][nt], 0, 0, 0);
            }
        }
    }

    if (is_unc) {
        // fused uncertainty head: relu(acc+ub1) dot uw2 over all 128 channels -> softplus
        const float* ub = bias + 256;
        float s[8] = {0.f, 0.f, 0.f, 0.f, 0.f, 0.f, 0.f, 0.f};
        #pragma unroll
        for (int mt = 0; mt < 4; ++mt) {
            const int mg = wm * 64 + mt * 16 + quad * 4;
            const float4 bi = *(const float4*)&ub[mg];
            const float4 uw = *(const float4*)&uw2[mg];
            #pragma unroll
            for (int nt = 0; nt < 8; ++nt) {
                s[nt] += fmaxf(acc[mt][nt][0] + bi.x, 0.f) * uw.x
                       + fmaxf(acc[mt][nt][1] + bi.y, 0.f) * uw.y
                       + fmaxf(acc[mt][nt][2] + bi.z, 0.f) * uw.z
                       + fmaxf(acc[mt][nt][3] + bi.w, 0.f) * uw.w;
            }
        }
        #pragma unroll
        for (int nt = 0; nt < 8; ++nt) {
            s[nt] += __shfl_xor(s[nt], 16);
            s[nt] += __shfl_xor(s[nt], 32);
        }
        if (quad == 0) {
            #pragma unroll
            for (int nt = 0; nt < 8; ++nt)
                usum[wm][wn * 128 + nt * 16 + lane16] = s[nt];
        }
        __syncthreads();
        {
            float x = usum[0][t] + usum[1][t] + ub2[0];
            uout[n0 + t] = fmaxf(x, 0.f) + log1pf(expf(-fabsf(x)));
        }
        return;
    }

    if (mode == 0) {
        // fused depth head: partial dot of relu(acc*scale+bias) with w3 (in uw2) over this
        // block's 128 channels; reduce quad via shfl, wm via LDS, one atomicAdd per pixel.
        float s[8] = {0.f, 0.f, 0.f, 0.f, 0.f, 0.f, 0.f, 0.f};
        #pragma unroll
        for (int mt = 0; mt < 4; ++mt) {
            const int mg = m0 + wm * 64 + mt * 16 + quad * 4;
            const float4 sc = *(const float4*)&scale[mg];
            const float4 bi = *(const float4*)&bias[mg];
            const float4 w  = *(const float4*)&uw2[mg];
            #pragma unroll
            for (int nt = 0; nt < 8; ++nt) {
                s[nt] += fmaxf(acc[mt][nt][0] * sc.x + bi.x, 0.f) * w.x
                       + fmaxf(acc[mt][nt][1] * sc.y + bi.y, 0.f) * w.y
                       + fmaxf(acc[mt][nt][2] * sc.z + bi.z, 0.f) * w.z
                       + fmaxf(acc[mt][nt][3] * sc.w + bi.w, 0.f) * w.w;
            }
        }
        #pragma unroll
        for (int nt = 0; nt < 8; ++nt) {
            s[nt] += __shfl_xor(s[nt], 16);
            s[nt] += __shfl_xor(s[nt], 32);
        }
        if (quad == 0) {
            #pragma unroll
            for (int nt = 0; nt < 8; ++nt)
                usum[wm][wn * 128 + nt * 16 + lane16] = s[nt];
        }
        __syncthreads();
        atomicAdd(&uout[n0 + t], usum[0][t] + usum[1][t]);
        return;
    }

    // mode 1 conv output: y = relu(acc*scale + bias) -> bf16 padded rows
    size_t obase[8];
    #pragma unroll
    for (int nt = 0; nt < 8; ++nt) {
        int n = n0 + wn * 128 + nt * 16 + lane16;
        int b = n / IMG, rem = n % IMG, yy = rem / WW, xx = rem % WW;
        obase[nt] = ((size_t)(b * PH + yy + 1) * PW + (xx + 1)) * 256;
    }
    #pragma unroll
    for (int mt = 0; mt < 4; ++mt) {
        const int mg = m0 + wm * 64 + mt * 16 + quad * 4;
        const float4 sc = *(const float4*)&scale[mg];
        const float4 bi = *(const float4*)&bias[mg];
        #pragma unroll
        for (int nt = 0; nt < 8; ++nt) {
            ushort4 pk;
            pk.x = f2bf(fmaxf(acc[mt][nt][0] * sc.x + bi.x, 0.f));
            pk.y = f2bf(fmaxf(acc[mt][nt][1] * sc.y + bi.y, 0.f));
            pk.z = f2bf(fmaxf(acc[mt][nt][2] * sc.z + bi.z, 0.f));
            pk.w = f2bf(fmaxf(acc[mt][nt][3] * sc.w + bi.w, 0.f));
            *(ushort4*)&outT[obase[nt] + mg] = pk;
        }
    }
}

// ---------------- finalize: depth transform (480 blocks) + per-box median (512 blocks) ----------
// Monotone-map median (r11): T(x) = 1/(0.01+9.99*sigmoid(x+b3)) is strictly DECREASING, and
// +b3 is order-preserving, so lower-median of transformed values = T(raw-ascending element at
// index wh>>1). Median blocks therefore radix-select directly on RAW conv2 sums (racc) using
// order-preserving float keys (u&MSB ? ~u : u|MSB) — independent of the transform blocks, so
// both roles run in ONE launch (kills the separate depth_transform kernel). Identical T
// expression in both paths -> bit-identical obj vs transform-then-median.
__global__ __launch_bounds__(256) void finalize(
    const float* __restrict__ racc, const float* __restrict__ b3,
    float* __restrict__ out, const int* __restrict__ bboxes, float* __restrict__ obj)
{
    const int t = threadIdx.x;
    if (blockIdx.x < 480) {
        int i = blockIdx.x * 256 + t;       // 480*256 = NPIX
        float x = racc[i] + b3[0];
        float sig = 1.f / (1.f + expf(-x));
        out[i] = 1.f / (0.01f + 9.99f * sig);
        return;
    }
    const int bi = blockIdx.x - 480;        // b*64 + box
    const int b = bi >> 6;
    const int* bb = bboxes + (size_t)bi * 4;
    int x1 = max(bb[0], 0), y1 = max(bb[1], 0);
    int x2 = min(bb[2], WW), y2 = min(bb[3], HH);
    int w = x2 - x1, h = y2 - y1;
    if (w <= 0 || h <= 0) {
        if (t == 0) obj[bi] = 0.f;
        return;
    }
    const int wh = w * h;
    int tgt = wh >> 1;                  // raw-ascending index == transformed lower median
    const float* dbase = racc + (size_t)b * IMG;

    __shared__ unsigned int hist[4][256];   // wave-private histograms
    __shared__ unsigned int wsum[4];
    __shared__ unsigned int sel_prefix, sel_target;
    unsigned int prefix = 0;
    const int g = t >> 6, gl = t & 63;  // wave and lane

    for (int pass = 0; pass < 4; ++pass) {
        const int shift = 24 - 8 * pass;
        #pragma unroll
        for (int k = 0; k < 4; ++k) hist[k][t & 255] = 0;
        __syncthreads();
        const unsigned int mask_high = (pass == 0) ? 0u : (0xFFFFFFFFu << (shift + 8));
        const unsigned int want = prefix & mask_high;
        for (int yy = y1 + g; yy < y2; yy += 4) {
            const float* row = dbase + yy * WW;
            for (int xx = x1 + gl; xx < x2; xx += 64) {
                unsigned int uu = __float_as_uint(row[xx]);
                unsigned int key = (uu & 0x80000000u) ? ~uu : (uu | 0x80000000u);
                bool pred = (key & mask_high) == want;
                unsigned int bin = (key >> shift) & 255;
                unsigned long long act = __ballot(pred);
                if (act != 0ull) {
                    int leader = __ffsll(act) - 1;
                    unsigned int lbin = __shfl(bin, leader);
                    unsigned long long same = __ballot(pred && (bin == lbin));
                    if (same == act) {
                        if (gl == leader)
                            atomicAdd(&hist[g][lbin], (unsigned int)__popcll(act));
                    } else if (pred) {
                        atomicAdd(&hist[g][bin], 1u);
                    }
                }
            }
        }
        __syncthreads();
        // parallel select: sum 4 wave-hists, inclusive scan across 256 threads
        unsigned int c = hist[0][t] + hist[1][t] + hist[2][t] + hist[3][t];
        unsigned int v = c;
        #pragma unroll
        for (int d = 1; d < 64; d <<= 1) {
            unsigned int n = __shfl_up(v, d);
            if (gl >= d) v += n;
        }
        if (gl == 63) wsum[g] = v;
        __syncthreads();
        unsigned int addv = 0;
        #pragma unroll
        for (int wv = 0; wv < 4; ++wv) addv += (wv < g) ? wsum[wv] : 0u;
        v += addv;
        unsigned int excl = v - c;
        if (excl <= (unsigned int)tgt && (unsigned int)tgt < v) {
            sel_prefix = prefix | ((unsigned int)t << shift);
            sel_target = (unsigned int)tgt - excl;
        }
        __syncthreads();
        prefix = sel_prefix;
        tgt = (int)sel_target;
        __syncthreads();
    }
    if (t == 0) {
        unsigned int key = prefix;
        unsigned int u = (key & 0x80000000u) ? (key ^ 0x80000000u) : ~key;
        float x = __uint_as_float(u) + b3[0];
        float sig = 1.f / (1.f + expf(-x));
        obj[bi] = 1.f / (0.01f + 9.99f * sig);
    }
}

extern "C" void kernel_launch(void* const* d_in, const int* in_sizes, int n_in,
                              void* d_out, int out_size, void* d_ws, size_t ws_size,
                              hipStream_t stream) {
    const float* features = (const float*)d_in[0];
    const int*   bboxes   = (const int*)d_in[1];
    const float* w1  = (const float*)d_in[2];
    const float* b1  = (const float*)d_in[3];
    const float* g1  = (const float*)d_in[4];
    const float* be1 = (const float*)d_in[5];
    const float* m1  = (const float*)d_in[6];
    const float* v1  = (const float*)d_in[7];
    const float* w2  = (const float*)d_in[8];
    const float* b2  = (const float*)d_in[9];
    const float* g2  = (const float*)d_in[10];
    const float* be2 = (const float*)d_in[11];
    const float* m2  = (const float*)d_in[12];
    const float* v2  = (const float*)d_in[13];
    const float* w3  = (const float*)d_in[14];
    const float* b3  = (const float*)d_in[15];
    const float* uw1 = (const float*)d_in[16];
    const float* ub1 = (const float*)d_in[17];
    const float* uw2 = (const float*)d_in[18];
    const float* ub2 = (const float*)d_in[19];
    float* out = (float*)d_out;

    char* ws = (char*)d_ws;
    // layout (bytes). Padded buffers have 8 KB read-slack gaps on both sides.
    unsigned short* featP = (unsigned short*)(ws + 8192);        // 65,028,096 -> end 65,036,288
    unsigned short* h1P   = (unsigned short*)(ws + 65044480);    // end 130,072,576
    unsigned short* w1T   = (unsigned short*)(ws + 130080768);   // 256 rows, 1,179,648 B
    unsigned short* uw1T  = w1T + 256 * 2304;                    // 128 rows right after -> combined 384
    unsigned short* w2T   = uw1T + 128 * 2304;                   // 1,179,648 B
    float* scale1 = (float*)(w2T + 589824);                      // 384
    float* bias1  = scale1 + 384;                                // 384 (256 BN-fold + 128 ub1)
    float* scale2 = bias1 + 384;                                 // 256
    float* bias2  = scale2 + 256;                                // 256
    float* racc   = (float*)(ws + 133036032);                    // raw depth sums, NPIX f32

    // single merged prep launch: weights transpose + pads + racc-zero + scalars + feature pack
    prep_all<<<9089, 256, 0, stream>>>(
        w1, w2, uw1, w1T, w2T, uw1T,
        (unsigned int*)featP, (unsigned int*)h1P, racc,
        b1, g1, be1, m1, v1, b2, g2, be2, m2, v2, ub1,
        scale1, bias1, scale2, bias2,
        features, featP);

    // merged conv1 (BN+ReLU, padded out) + fused uncertainty head; My=3, 1440 blocks (256n tiles)
    conv3x3_mfma<<<1440, 256, 0, stream>>>(
        featP, w1T, scale1, bias1, h1P, out + NPIX, uw2, ub2, 256, 1, 3);
    // conv2 + fused depth head: atomicAdd RAW partial dots into racc; My=2, 960 blocks
    conv3x3_mfma<<<960, 256, 0, stream>>>(
        h1P, w2T, scale2, bias2, nullptr, racc, w3, nullptr, 256, 0, 2);

    // transform (480 blocks) + median-on-raw (512 blocks) in one launch
    finalize<<<992, 256, 0, stream>>>(racc, b3, out, bboxes, out + 2 * NPIX);
}